// Round 1
// baseline (1134.224 us; speedup 1.0000x reference)
//
#include <hip/hip_runtime.h>
#include <math.h>

// Problem constants (Attention_Block_9199819948230)
#define BB 4
#define SS 1024
#define DD 1024
#define HH 16
#define DHH 64
#define BHH (BB * HH)
#define LDSP 68  // padded LDS row stride (floats) for 64-wide tiles; 68%32==4 keeps b128 reads ~conflict-free

// Workspace layout (float offsets)
#define CTX_OFF  ((size_t)0)                         // 4M floats
#define X_OFF    ((size_t)4 * 1024 * 1024)           // 4M floats
#define PMAX_OFF ((size_t)8 * 1024 * 1024)           // 1M floats (BH*S*16)
#define PSUM_OFF ((size_t)9 * 1024 * 1024)           // 1M floats
#define ROWM_OFF ((size_t)10 * 1024 * 1024)          // 64K floats
#define ROWL_OFF (ROWM_OFF + 65536)                  // 64K floats

// ---- shared helpers -------------------------------------------------------

// Stage a 64x64 tile from global row-major (rowStride floats) into LDS
// TRANSPOSED: dst[k][m], dst row stride LDSP. src pre-offset to (m0,k0).
__device__ __forceinline__ void stage_T(const float* __restrict__ src, int rowStride,
                                        float* __restrict__ dst, int tid) {
#pragma unroll
  for (int u = 0; u < 4; ++u) {
    int f = tid + 256 * u;        // float4 id in [0,1024)
    int m = f >> 4;               // 0..63
    int k4 = (f & 15) << 2;       // 0,4,...,60
    float4 v = *reinterpret_cast<const float4*>(src + (size_t)m * rowStride + k4);
    dst[(k4 + 0) * LDSP + m] = v.x;
    dst[(k4 + 1) * LDSP + m] = v.y;
    dst[(k4 + 2) * LDSP + m] = v.z;
    dst[(k4 + 3) * LDSP + m] = v.w;
  }
}

// Stage a 64x64 tile WITHOUT transpose: dst[k][c] = src[k*rowStride + c].
__device__ __forceinline__ void stage_N(const float* __restrict__ src, int rowStride,
                                        float* __restrict__ dst, int tid) {
#pragma unroll
  for (int u = 0; u < 4; ++u) {
    int f = tid + 256 * u;
    int kk = f >> 4;
    int c4 = (f & 15) << 2;
    float4 v = *reinterpret_cast<const float4*>(src + (size_t)kk * rowStride + c4);
    *reinterpret_cast<float4*>(dst + kk * LDSP + c4) = v;
  }
}

// 64x64 tile inner product: acc[i][j] += sum_k As[k][ty*4+i] * Bs[k][tx*4+j]
__device__ __forceinline__ void mm64(const float* __restrict__ As, const float* __restrict__ Bs,
                                     int tx, int ty, float acc[4][4]) {
#pragma unroll 4
  for (int kk = 0; kk < 64; ++kk) {
    float4 a = *reinterpret_cast<const float4*>(As + kk * LDSP + ty * 4);
    float4 b = *reinterpret_cast<const float4*>(Bs + kk * LDSP + tx * 4);
    float av[4] = {a.x, a.y, a.z, a.w};
    float bv[4] = {b.x, b.y, b.z, b.w};
#pragma unroll
    for (int i = 0; i < 4; ++i)
#pragma unroll
      for (int j = 0; j < 4; ++j) acc[i][j] = fmaf(av[i], bv[j], acc[i][j]);
  }
}

// ---- K1: att_scores = QK^T/8 + c*scores - 1e8*(1-mask); also per-tile softmax partials
__global__ __launch_bounds__(256) void qk_scores_kernel(
    const float* __restrict__ q, const float* __restrict__ k,
    const float* __restrict__ scores, const float* __restrict__ mask,
    const float* __restrict__ c, float* __restrict__ att,
    float* __restrict__ pmax, float* __restrict__ psum) {
  __shared__ float As[64 * LDSP];
  __shared__ float Bs[64 * LDSP];
  int tid = threadIdx.x;
  int tx = tid & 15, ty = tid >> 4;
  int kt = blockIdx.x, qt = blockIdx.y, bh = blockIdx.z;
  int b = bh >> 4, h = bh & 15;
  int qr0 = qt * 64, kr0 = kt * 64;

  stage_T(q + ((size_t)(b * SS + qr0)) * DD + h * DHH, DD, As, tid);
  stage_T(k + ((size_t)(b * SS + kr0)) * DD + h * DHH, DD, Bs, tid);
  __syncthreads();
  float acc[4][4] = {{0.f}};
  mm64(As, Bs, tx, ty, acc);

  float cc = c[0];
  float4 mv = *reinterpret_cast<const float4*>(mask + b * SS + kr0 + tx * 4);
  float mb[4] = {-1e8f * (1.0f - mv.x), -1e8f * (1.0f - mv.y),
                 -1e8f * (1.0f - mv.z), -1e8f * (1.0f - mv.w)};
#pragma unroll
  for (int i = 0; i < 4; ++i) {
    int r = qr0 + ty * 4 + i;
    size_t rowoff = ((size_t)(bh * SS + r)) * SS + kr0 + tx * 4;
    float4 sc = *reinterpret_cast<const float4*>(scores + rowoff);
    float sv[4] = {sc.x, sc.y, sc.z, sc.w};
    float o[4];
#pragma unroll
    for (int j = 0; j < 4; ++j) o[j] = acc[i][j] * 0.125f + cc * sv[j] + mb[j];
    float4 ov = {o[0], o[1], o[2], o[3]};
    *reinterpret_cast<float4*>(att + rowoff) = ov;
    // per-(row, 64-col-tile) softmax partials: tile max + sum(exp(.-max))
    float m = fmaxf(fmaxf(o[0], o[1]), fmaxf(o[2], o[3]));
    float l = __expf(o[0] - m) + __expf(o[1] - m) + __expf(o[2] - m) + __expf(o[3] - m);
#pragma unroll
    for (int off = 8; off >= 1; off >>= 1) {  // 16 threads (same ty,i) share a row
      float m2 = __shfl_xor(m, off);
      float l2 = __shfl_xor(l, off);
      float nm = fmaxf(m, m2);
      l = l * __expf(m - nm) + l2 * __expf(m2 - nm);
      m = nm;
    }
    if (tx == 0) {
      pmax[((size_t)(bh * SS + r)) * 16 + kt] = m;
      psum[((size_t)(bh * SS + r)) * 16 + kt] = l;
    }
  }
}

// ---- K2: reduce 16 tile-partials per row -> row max, 1/row-sum
__global__ __launch_bounds__(256) void stats_reduce_kernel(
    const float* __restrict__ pmax, const float* __restrict__ psum,
    float* __restrict__ rowm, float* __restrict__ rowinvl) {
  int idx = blockIdx.x * 256 + threadIdx.x;  // [0, BH*S)
  const float* pm = pmax + (size_t)idx * 16;
  const float* pl = psum + (size_t)idx * 16;
  float m = pm[0], l = pl[0];
#pragma unroll
  for (int t = 1; t < 16; ++t) {
    float m2 = pm[t], l2 = pl[t];
    float nm = fmaxf(m, m2);
    l = l * __expf(m - nm) + l2 * __expf(m2 - nm);
    m = nm;
  }
  rowm[idx] = m;
  rowinvl[idx] = 1.0f / l;
}

// ---- K3: ctx = softmax(att) @ V, softmax applied on the fly
__global__ __launch_bounds__(256) void ctx_kernel(
    const float* __restrict__ att, const float* __restrict__ v,
    const float* __restrict__ rowm, const float* __restrict__ rowinvl,
    float* __restrict__ ctx) {
  __shared__ float Ps[64 * LDSP];
  __shared__ float Vs[64 * LDSP];
  int tid = threadIdx.x;
  int tx = tid & 15, ty = tid >> 4;
  int qt = blockIdx.x, bh = blockIdx.y;
  int b = bh >> 4, h = bh & 15;
  int qr0 = qt * 64;
  float acc[4][4] = {{0.f}};
  for (int kc = 0; kc < SS; kc += 64) {
    // stage P transposed, applying p = exp(s - m) * invl during the copy
#pragma unroll
    for (int u = 0; u < 4; ++u) {
      int f = tid + 256 * u;
      int m_ = f >> 4;
      int k4 = (f & 15) << 2;
      int gr = bh * SS + qr0 + m_;
      float4 sv = *reinterpret_cast<const float4*>(att + (size_t)gr * SS + kc + k4);
      float mm = rowm[gr];
      float il = rowinvl[gr];
      Ps[(k4 + 0) * LDSP + m_] = __expf(sv.x - mm) * il;
      Ps[(k4 + 1) * LDSP + m_] = __expf(sv.y - mm) * il;
      Ps[(k4 + 2) * LDSP + m_] = __expf(sv.z - mm) * il;
      Ps[(k4 + 3) * LDSP + m_] = __expf(sv.w - mm) * il;
    }
    stage_N(v + ((size_t)(b * SS + kc)) * DD + h * DHH, DD, Vs, tid);
    __syncthreads();
    mm64(Ps, Vs, tx, ty, acc);
    __syncthreads();
  }
#pragma unroll
  for (int i = 0; i < 4; ++i) {
    int r = qr0 + ty * 4 + i;
    float4 ov = {acc[i][0], acc[i][1], acc[i][2], acc[i][3]};
    *reinterpret_cast<float4*>(ctx + ((size_t)(b * SS + r)) * DD + h * DHH + tx * 4) = ov;
  }
}

// ---- K4: x = ctx @ W_proj^T  (NT GEMM 4096x1024x1024)
__global__ __launch_bounds__(256) void proj_kernel(
    const float* __restrict__ A, const float* __restrict__ W, float* __restrict__ X) {
  __shared__ float As[64 * LDSP];
  __shared__ float Bs[64 * LDSP];
  int tid = threadIdx.x;
  int tx = tid & 15, ty = tid >> 4;
  int d0 = blockIdx.x * 64, n0 = blockIdx.y * 64;
  float acc[4][4] = {{0.f}};
  for (int kc = 0; kc < DD; kc += 64) {
    stage_T(A + (size_t)n0 * DD + kc, DD, As, tid);
    stage_T(W + (size_t)d0 * DD + kc, DD, Bs, tid);
    __syncthreads();
    mm64(As, Bs, tx, ty, acc);
    __syncthreads();
  }
#pragma unroll
  for (int i = 0; i < 4; ++i) {
    float4 ov = {acc[i][0], acc[i][1], acc[i][2], acc[i][3]};
    *reinterpret_cast<float4*>(X + (size_t)(n0 + ty * 4 + i) * DD + d0 + tx * 4) = ov;
  }
}

// ---- K5: y_pre = q @ Wm[:, :D]^T + x @ Wm[:, D:]^T  (K = 2048)
__global__ __launch_bounds__(256) void minus_kernel(
    const float* __restrict__ q, const float* __restrict__ x,
    const float* __restrict__ Wm, float* __restrict__ Y) {
  __shared__ float As[64 * LDSP];
  __shared__ float Bs[64 * LDSP];
  int tid = threadIdx.x;
  int tx = tid & 15, ty = tid >> 4;
  int d0 = blockIdx.x * 64, n0 = blockIdx.y * 64;
  float acc[4][4] = {{0.f}};
  for (int kc = 0; kc < 2 * DD; kc += 64) {
    const float* asrc = (kc < DD) ? (q + (size_t)n0 * DD + kc)
                                  : (x + (size_t)n0 * DD + (kc - DD));
    stage_T(asrc, DD, As, tid);
    stage_T(Wm + (size_t)d0 * (2 * DD) + kc, 2 * DD, Bs, tid);
    __syncthreads();
    mm64(As, Bs, tx, ty, acc);
    __syncthreads();
  }
#pragma unroll
  for (int i = 0; i < 4; ++i) {
    float4 ov = {acc[i][0], acc[i][1], acc[i][2], acc[i][3]};
    *reinterpret_cast<float4*>(Y + (size_t)(n0 + ty * 4 + i) * DD + d0 + tx * 4) = ov;
  }
}

// ---- K6: in-place LayerNorm over last dim (1024) of y
__global__ __launch_bounds__(256) void ln_kernel(
    float* __restrict__ Y, const float* __restrict__ w, const float* __restrict__ b) {
  __shared__ float ps[4], ps2[4];
  int row = blockIdx.x, t = threadIdx.x;
  float* rp = Y + (size_t)row * DD;
  float4 v = *reinterpret_cast<const float4*>(rp + t * 4);
  float s = v.x + v.y + v.z + v.w;
  float s2 = v.x * v.x + v.y * v.y + v.z * v.z + v.w * v.w;
#pragma unroll
  for (int o = 32; o > 0; o >>= 1) {
    s += __shfl_down(s, o);
    s2 += __shfl_down(s2, o);
  }
  if ((t & 63) == 0) { ps[t >> 6] = s; ps2[t >> 6] = s2; }
  __syncthreads();
  s = ps[0] + ps[1] + ps[2] + ps[3];
  s2 = ps2[0] + ps2[1] + ps2[2] + ps2[3];
  float mu = s * (1.0f / DD);
  float var = s2 * (1.0f / DD) - mu * mu;
  float rs = rsqrtf(var + 1e-5f);
  float4 wv = *reinterpret_cast<const float4*>(w + t * 4);
  float4 bv = *reinterpret_cast<const float4*>(b + t * 4);
  float4 ov;
  ov.x = (v.x - mu) * rs * wv.x + bv.x;
  ov.y = (v.y - mu) * rs * wv.y + bv.y;
  ov.z = (v.z - mu) * rs * wv.z + bv.z;
  ov.w = (v.w - mu) * rs * wv.w + bv.w;
  *reinterpret_cast<float4*>(rp + t * 4) = ov;
}

extern "C" void kernel_launch(void* const* d_in, const int* in_sizes, int n_in,
                              void* d_out, int out_size, void* d_ws, size_t ws_size,
                              hipStream_t stream) {
  const float* q      = (const float*)d_in[0];
  const float* k      = (const float*)d_in[1];
  const float* v      = (const float*)d_in[2];
  const float* mask   = (const float*)d_in[3];
  const float* scores = (const float*)d_in[4];
  const float* W_proj = (const float*)d_in[5];
  const float* W_minus= (const float*)d_in[6];
  const float* ln_w   = (const float*)d_in[7];
  const float* ln_b   = (const float*)d_in[8];
  const float* c      = (const float*)d_in[9];

  float* y   = (float*)d_out;                       // (B,S,D)
  float* att = y + (size_t)BB * SS * DD;            // (B,H,S,S)

  float* ws      = (float*)d_ws;
  float* ctx     = ws + CTX_OFF;
  float* x       = ws + X_OFF;
  float* pmax    = ws + PMAX_OFF;
  float* psum    = ws + PSUM_OFF;
  float* rowm    = ws + ROWM_OFF;
  float* rowinvl = ws + ROWL_OFF;

  qk_scores_kernel<<<dim3(16, 16, BHH), 256, 0, stream>>>(q, k, scores, mask, c, att, pmax, psum);
  stats_reduce_kernel<<<dim3(256), 256, 0, stream>>>(pmax, psum, rowm, rowinvl);
  ctx_kernel<<<dim3(16, BHH), 256, 0, stream>>>(att, v, rowm, rowinvl, ctx);
  proj_kernel<<<dim3(16, 64), 256, 0, stream>>>(ctx, W_proj, x);
  minus_kernel<<<dim3(16, 64), 256, 0, stream>>>(q, x, W_minus, y);
  ln_kernel<<<dim3(BB * SS), 256, 0, stream>>>(y, ln_w, ln_b);
}

// Round 2
// 733.011 us; speedup vs baseline: 1.5473x; 1.5473x over previous
//
#include <hip/hip_runtime.h>
#include <hip/hip_bf16.h>
#include <math.h>

#define BB 4
#define SS 1024
#define DD 1024
#define HH 16
#define DHH 64
#define BHH (BB * HH)

#define LDB 88   // bf16 LDS row stride: 176B rows -> 16B aligned, 2-way-max conflicts (free)
#define LDC 68   // fp32 LDS row stride for epilogue staging (272B rows, 16B aligned)

typedef __attribute__((ext_vector_type(8))) short short8;   // 8 x bf16 (4 VGPRs)
typedef __attribute__((ext_vector_type(4))) float f32x4;    // MFMA accumulator

__device__ __forceinline__ unsigned short f2bf(float x) {
  __hip_bfloat16 h = __float2bfloat16(x);
  return *reinterpret_cast<unsigned short*>(&h);
}

// Stage 64x64 bf16 tile, global row-major (ld elems) -> LDS [64][LDB].
__device__ __forceinline__ void stageb(const unsigned short* __restrict__ src, int ld,
                                       unsigned short* __restrict__ dst, int tid) {
#pragma unroll
  for (int u = 0; u < 2; ++u) {
    int cidx = tid + 256 * u;      // 512 chunks of 8 bf16
    int r = cidx >> 3;
    int c8 = (cidx & 7) * 8;
    float4 v = *reinterpret_cast<const float4*>(src + (size_t)r * ld + c8);
    *reinterpret_cast<float4*>(dst + r * LDB + c8) = v;
  }
}

// A/B operand fragment: elem[idx = lane&15][k = kh + (lane>>4)*8 + j], j=0..7
__device__ __forceinline__ short8 ldfrag(const unsigned short* __restrict__ base,
                                         int row16, int kh, int lane) {
  const unsigned short* p = base + (size_t)(row16 + (lane & 15)) * LDB + kh + (lane >> 4) * 8;
  return *reinterpret_cast<const short8*>(p);
}

// 4 waves: wave w computes rows 0..63 x cols [w*16, w*16+16) of a 64x64 tile.
__device__ __forceinline__ void mfma_tile(const unsigned short* As, const unsigned short* Bs,
                                          int w, int lane, f32x4 acc[4]) {
#pragma unroll
  for (int kh = 0; kh < 64; kh += 32) {
    short8 b = ldfrag(Bs, w * 16, kh, lane);
#pragma unroll
    for (int mb = 0; mb < 4; ++mb) {
      short8 a = ldfrag(As, mb * 16, kh, lane);
      acc[mb] = __builtin_amdgcn_mfma_f32_16x16x32_bf16(a, b, acc[mb], 0, 0, 0);
    }
  }
}

// acc -> LDS fp32 [64][LDC] (row = mb*16 + quad*4 + r, col = w*16 + lane&15)
__device__ __forceinline__ void acc_to_lds(float* Cs, const f32x4 acc[4], int w, int lane,
                                           float scale) {
  int quad = lane >> 4, col = w * 16 + (lane & 15);
#pragma unroll
  for (int mb = 0; mb < 4; ++mb)
#pragma unroll
    for (int r = 0; r < 4; ++r)
      Cs[(mb * 16 + quad * 4 + r) * LDC + col] = acc[mb][r] * scale;
}

// ---- K0a: fp32 -> bf16 elementwise
__global__ __launch_bounds__(256) void cvt_kernel(const float* __restrict__ in,
                                                  unsigned short* __restrict__ out, int n4) {
  int i = blockIdx.x * 256 + threadIdx.x;
  if (i < n4) {
    float4 v = reinterpret_cast<const float4*>(in)[i];
    ushort4 o;
    o.x = f2bf(v.x); o.y = f2bf(v.y); o.z = f2bf(v.z); o.w = f2bf(v.w);
    reinterpret_cast<ushort4*>(out)[i] = o;
  }
}

// ---- K0b: v (B,S,H,DH) -> vT bf16 [bh][d][s]
__global__ __launch_bounds__(256) void vtrans_kernel(const float* __restrict__ v,
                                                     unsigned short* __restrict__ vT) {
  __shared__ unsigned short T[64 * LDC];
  int tid = threadIdx.x;
  int s0 = blockIdx.x * 64, bh = blockIdx.y;
  int b = bh >> 4, h = bh & 15;
#pragma unroll
  for (int u = 0; u < 4; ++u) {
    int f = tid + 256 * u;
    int r = f >> 4, c4 = (f & 15) * 4;
    float4 vv = *reinterpret_cast<const float4*>(v + ((size_t)(b * SS + s0 + r)) * DD + h * DHH + c4);
    T[(c4 + 0) * LDC + r] = f2bf(vv.x);
    T[(c4 + 1) * LDC + r] = f2bf(vv.y);
    T[(c4 + 2) * LDC + r] = f2bf(vv.z);
    T[(c4 + 3) * LDC + r] = f2bf(vv.w);
  }
  __syncthreads();
#pragma unroll
  for (int u = 0; u < 4; ++u) {
    int f = tid + 256 * u;
    int d = f >> 4, s4 = (f & 15) * 4;
    ushort4 o = *reinterpret_cast<const ushort4*>(&T[d * LDC + s4]);
    *reinterpret_cast<ushort4*>(vT + ((size_t)(bh * DHH + d)) * SS + s0 + s4) = o;
  }
}

// ---- K1: att = QK^T/8 + c*scores + mask ; per-(row,64tile) softmax partials
__global__ __launch_bounds__(256) void qk_mfma_kernel(
    const unsigned short* __restrict__ qb, const unsigned short* __restrict__ kb,
    const float* __restrict__ scores, const float* __restrict__ mask,
    const float* __restrict__ c, float* __restrict__ att,
    float* __restrict__ pmax, float* __restrict__ psum) {
  __shared__ unsigned short smem[2 * 64 * LDB];
  unsigned short* As = smem;
  unsigned short* Bs = smem + 64 * LDB;
  float* Cs = reinterpret_cast<float*>(smem);
  int tid = threadIdx.x, lane = tid & 63, w = tid >> 6;
  int kt = blockIdx.x, qt = blockIdx.y, bh = blockIdx.z;
  int b = bh >> 4, h = bh & 15;
  int qr0 = qt * 64, kr0 = kt * 64;

  stageb(qb + ((size_t)(b * SS + qr0)) * DD + h * DHH, DD, As, tid);
  stageb(kb + ((size_t)(b * SS + kr0)) * DD + h * DHH, DD, Bs, tid);
  __syncthreads();
  f32x4 acc[4] = {};
  mfma_tile(As, Bs, w, lane, acc);
  __syncthreads();
  acc_to_lds(Cs, acc, w, lane, 0.125f);
  __syncthreads();

  float cc = c[0];
#pragma unroll
  for (int u = 0; u < 4; ++u) {
    int f = tid + 256 * u;
    int row = f >> 4, c4 = (f & 15) * 4;
    int rg = bh * SS + qr0 + row;
    size_t goff = (size_t)rg * SS + kr0 + c4;
    float4 qk = *reinterpret_cast<const float4*>(&Cs[row * LDC + c4]);
    float4 sc = *reinterpret_cast<const float4*>(scores + goff);
    float4 mv = *reinterpret_cast<const float4*>(mask + b * SS + kr0 + c4);
    float o0 = qk.x + cc * sc.x - 1e8f * (1.0f - mv.x);
    float o1 = qk.y + cc * sc.y - 1e8f * (1.0f - mv.y);
    float o2 = qk.z + cc * sc.z - 1e8f * (1.0f - mv.z);
    float o3 = qk.w + cc * sc.w - 1e8f * (1.0f - mv.w);
    float4 ov = {o0, o1, o2, o3};
    *reinterpret_cast<float4*>(att + goff) = ov;
    float m = fmaxf(fmaxf(o0, o1), fmaxf(o2, o3));
#pragma unroll
    for (int off = 1; off <= 8; off <<= 1) m = fmaxf(m, __shfl_xor(m, off));
    float l = __expf(o0 - m) + __expf(o1 - m) + __expf(o2 - m) + __expf(o3 - m);
#pragma unroll
    for (int off = 1; off <= 8; off <<= 1) l += __shfl_xor(l, off);
    if ((tid & 15) == 0) {
      pmax[(size_t)rg * 16 + kt] = m;
      psum[(size_t)rg * 16 + kt] = l;
    }
  }
}

// ---- K2: reduce 16 tile-partials per row
__global__ __launch_bounds__(256) void stats_reduce_kernel(
    const float* __restrict__ pmax, const float* __restrict__ psum,
    float* __restrict__ rowm, float* __restrict__ rowinvl) {
  int idx = blockIdx.x * 256 + threadIdx.x;
  const float* pm = pmax + (size_t)idx * 16;
  const float* pl = psum + (size_t)idx * 16;
  float m = pm[0], l = pl[0];
#pragma unroll
  for (int t = 1; t < 16; ++t) {
    float m2 = pm[t], l2 = pl[t];
    float nm = fmaxf(m, m2);
    l = l * __expf(m - nm) + l2 * __expf(m2 - nm);
    m = nm;
  }
  rowm[idx] = m;
  rowinvl[idx] = 1.0f / l;
}

// ---- K3: ctxb = softmax(att) @ V (bf16 MFMA, P built on the fly)
__global__ __launch_bounds__(256) void ctx_mfma_kernel(
    const float* __restrict__ att, const unsigned short* __restrict__ vT,
    const float* __restrict__ rowm, const float* __restrict__ rowinvl,
    unsigned short* __restrict__ ctxb) {
  __shared__ unsigned short smem[2 * 64 * LDB];
  unsigned short* As = smem;
  unsigned short* Bs = smem + 64 * LDB;
  float* Cs = reinterpret_cast<float*>(smem);
  int tid = threadIdx.x, lane = tid & 63, w = tid >> 6;
  int qt = blockIdx.x, bh = blockIdx.y;
  int b = bh >> 4, h = bh & 15;
  int qr0 = qt * 64;
  f32x4 acc[4] = {};
  for (int kc = 0; kc < SS; kc += 64) {
#pragma unroll
    for (int u = 0; u < 4; ++u) {
      int f = tid + 256 * u;
      int row = f >> 4, c4 = (f & 15) * 4;
      int rg = bh * SS + qr0 + row;
      float4 s = *reinterpret_cast<const float4*>(att + (size_t)rg * SS + kc + c4);
      float mr = rowm[rg], il = rowinvl[rg];
      ushort4 pv;
      pv.x = f2bf(__expf(s.x - mr) * il);
      pv.y = f2bf(__expf(s.y - mr) * il);
      pv.z = f2bf(__expf(s.z - mr) * il);
      pv.w = f2bf(__expf(s.w - mr) * il);
      *reinterpret_cast<ushort4*>(&As[row * LDB + c4]) = pv;
    }
    stageb(vT + (size_t)bh * DHH * SS + kc, SS, Bs, tid);
    __syncthreads();
    mfma_tile(As, Bs, w, lane, acc);
    __syncthreads();
  }
  acc_to_lds(Cs, acc, w, lane, 1.0f);
  __syncthreads();
#pragma unroll
  for (int u = 0; u < 4; ++u) {
    int f = tid + 256 * u;
    int row = f >> 4, c4 = (f & 15) * 4;
    float4 vv = *reinterpret_cast<const float4*>(&Cs[row * LDC + c4]);
    ushort4 o;
    o.x = f2bf(vv.x); o.y = f2bf(vv.y); o.z = f2bf(vv.z); o.w = f2bf(vv.w);
    *reinterpret_cast<ushort4*>(ctxb + ((size_t)(b * SS + qr0 + row)) * DD + h * DHH + c4) = o;
  }
}

// ---- K4: xb = ctxb @ Wp^T (bf16 in/out)
__global__ __launch_bounds__(256) void proj_mfma_kernel(
    const unsigned short* __restrict__ A, const unsigned short* __restrict__ W,
    unsigned short* __restrict__ X) {
  __shared__ unsigned short smem[2 * 64 * LDB];
  unsigned short* As = smem;
  unsigned short* Bs = smem + 64 * LDB;
  float* Cs = reinterpret_cast<float*>(smem);
  int tid = threadIdx.x, lane = tid & 63, w = tid >> 6;
  int d0 = blockIdx.x * 64, n0 = blockIdx.y * 64;
  f32x4 acc[4] = {};
  for (int kc = 0; kc < DD; kc += 64) {
    stageb(A + (size_t)n0 * DD + kc, DD, As, tid);
    stageb(W + (size_t)d0 * DD + kc, DD, Bs, tid);
    __syncthreads();
    mfma_tile(As, Bs, w, lane, acc);
    __syncthreads();
  }
  acc_to_lds(Cs, acc, w, lane, 1.0f);
  __syncthreads();
#pragma unroll
  for (int u = 0; u < 4; ++u) {
    int f = tid + 256 * u;
    int row = f >> 4, c4 = (f & 15) * 4;
    float4 vv = *reinterpret_cast<const float4*>(&Cs[row * LDC + c4]);
    ushort4 o;
    o.x = f2bf(vv.x); o.y = f2bf(vv.y); o.z = f2bf(vv.z); o.w = f2bf(vv.w);
    *reinterpret_cast<ushort4*>(X + (size_t)(n0 + row) * DD + d0 + c4) = o;
  }
}

// ---- K5: y = [q | x] @ Wm^T (K=2048), fp32 out
__global__ __launch_bounds__(256) void minus_mfma_kernel(
    const unsigned short* __restrict__ qb, const unsigned short* __restrict__ xb,
    const unsigned short* __restrict__ Wm, float* __restrict__ Y) {
  __shared__ unsigned short smem[2 * 64 * LDB];
  unsigned short* As = smem;
  unsigned short* Bs = smem + 64 * LDB;
  float* Cs = reinterpret_cast<float*>(smem);
  int tid = threadIdx.x, lane = tid & 63, w = tid >> 6;
  int d0 = blockIdx.x * 64, n0 = blockIdx.y * 64;
  f32x4 acc[4] = {};
  for (int kc = 0; kc < 2 * DD; kc += 64) {
    const unsigned short* asrc = (kc < DD) ? (qb + (size_t)n0 * DD + kc)
                                           : (xb + (size_t)n0 * DD + (kc - DD));
    stageb(asrc, DD, As, tid);
    stageb(Wm + (size_t)d0 * (2 * DD) + kc, 2 * DD, Bs, tid);
    __syncthreads();
    mfma_tile(As, Bs, w, lane, acc);
    __syncthreads();
  }
  acc_to_lds(Cs, acc, w, lane, 1.0f);
  __syncthreads();
#pragma unroll
  for (int u = 0; u < 4; ++u) {
    int f = tid + 256 * u;
    int row = f >> 4, c4 = (f & 15) * 4;
    float4 vv = *reinterpret_cast<const float4*>(&Cs[row * LDC + c4]);
    *reinterpret_cast<float4*>(Y + (size_t)(n0 + row) * DD + d0 + c4) = vv;
  }
}

// ---- K6: in-place LayerNorm over last dim (1024)
__global__ __launch_bounds__(256) void ln_kernel(
    float* __restrict__ Y, const float* __restrict__ w, const float* __restrict__ b) {
  __shared__ float ps[4], ps2[4];
  int row = blockIdx.x, t = threadIdx.x;
  float* rp = Y + (size_t)row * DD;
  float4 v = *reinterpret_cast<const float4*>(rp + t * 4);
  float s = v.x + v.y + v.z + v.w;
  float s2 = v.x * v.x + v.y * v.y + v.z * v.z + v.w * v.w;
#pragma unroll
  for (int o = 32; o > 0; o >>= 1) {
    s += __shfl_down(s, o);
    s2 += __shfl_down(s2, o);
  }
  if ((t & 63) == 0) { ps[t >> 6] = s; ps2[t >> 6] = s2; }
  __syncthreads();
  s = ps[0] + ps[1] + ps[2] + ps[3];
  s2 = ps2[0] + ps2[1] + ps2[2] + ps2[3];
  float mu = s * (1.0f / DD);
  float var = s2 * (1.0f / DD) - mu * mu;
  float rs = rsqrtf(var + 1e-5f);
  float4 wv = *reinterpret_cast<const float4*>(w + t * 4);
  float4 bv = *reinterpret_cast<const float4*>(b + t * 4);
  float4 ov;
  ov.x = (v.x - mu) * rs * wv.x + bv.x;
  ov.y = (v.y - mu) * rs * wv.y + bv.y;
  ov.z = (v.z - mu) * rs * wv.z + bv.z;
  ov.w = (v.w - mu) * rs * wv.w + bv.w;
  *reinterpret_cast<float4*>(rp + t * 4) = ov;
}

extern "C" void kernel_launch(void* const* d_in, const int* in_sizes, int n_in,
                              void* d_out, int out_size, void* d_ws, size_t ws_size,
                              hipStream_t stream) {
  const float* q      = (const float*)d_in[0];
  const float* k      = (const float*)d_in[1];
  const float* v      = (const float*)d_in[2];
  const float* mask   = (const float*)d_in[3];
  const float* scores = (const float*)d_in[4];
  const float* W_proj = (const float*)d_in[5];
  const float* W_minus= (const float*)d_in[6];
  const float* ln_w   = (const float*)d_in[7];
  const float* ln_b   = (const float*)d_in[8];
  const float* c      = (const float*)d_in[9];

  float* y   = (float*)d_out;             // (B,S,D)
  float* att = y + (size_t)BB * SS * DD;  // (B,H,S,S)

  const size_t MB = 1u << 20;
  char* w = (char*)d_ws;
  unsigned short* qb   = (unsigned short*)(w);             // 8 MB
  unsigned short* kb   = (unsigned short*)(w + 8 * MB);    // 8 MB
  unsigned short* vT   = (unsigned short*)(w + 16 * MB);   // 8 MB
  unsigned short* Wpb  = (unsigned short*)(w + 24 * MB);   // 2 MB
  unsigned short* Wmb  = (unsigned short*)(w + 26 * MB);   // 4 MB
  unsigned short* ctxb = (unsigned short*)(w + 30 * MB);   // 8 MB
  unsigned short* xb   = (unsigned short*)(w + 38 * MB);   // 8 MB
  float* pmax    = (float*)(w + 46 * MB);                  // 4 MB
  float* psum    = (float*)(w + 50 * MB);                  // 4 MB
  float* rowm    = (float*)(w + 54 * MB);                  // 256 KB
  float* rowinvl = (float*)(w + 54 * MB + 256 * 1024);     // 256 KB

  const int NQ = BB * SS * DD;  // 4M
  cvt_kernel<<<dim3(NQ / 4 / 256), 256, 0, stream>>>(q, qb, NQ / 4);
  cvt_kernel<<<dim3(NQ / 4 / 256), 256, 0, stream>>>(k, kb, NQ / 4);
  cvt_kernel<<<dim3(DD * DD / 4 / 256), 256, 0, stream>>>(W_proj, Wpb, DD * DD / 4);
  cvt_kernel<<<dim3(2 * DD * DD / 4 / 256), 256, 0, stream>>>(W_minus, Wmb, 2 * DD * DD / 4);
  vtrans_kernel<<<dim3(16, BHH), 256, 0, stream>>>(v, vT);

  qk_mfma_kernel<<<dim3(16, 16, BHH), 256, 0, stream>>>(qb, kb, scores, mask, c, att, pmax, psum);
  stats_reduce_kernel<<<dim3(256), 256, 0, stream>>>(pmax, psum, rowm, rowinvl);
  ctx_mfma_kernel<<<dim3(16, BHH), 256, 0, stream>>>(att, vT, rowm, rowinvl, ctxb);
  proj_mfma_kernel<<<dim3(16, 64), 256, 0, stream>>>(ctxb, Wpb, xb);
  minus_mfma_kernel<<<dim3(16, 64), 256, 0, stream>>>(qb, xb, Wmb, y);
  ln_kernel<<<dim3(BB * SS), 256, 0, stream>>>(y, ln_w, ln_b);
}